// Round 16
// baseline (285.914 us; speedup 1.0000x reference)
//
#include <hip/hip_runtime.h>
#include <hip/hip_bf16.h>

// ---------------------------------------------------------------------------
// AdaptiveSTSamplingMixing — MI355X implementation
// R15: fix R14 compile error (k_feat_transpose_all defined after use).
//      Logic identical to R14: taps in global tapbuf (uniform s_load ->
//      SGPRs), arena offsets folded, no LDS tap arrays in sample branch.
// ---------------------------------------------------------------------------

typedef __attribute__((ext_vector_type(8))) short bf16x8;   // 8 bf16 in 4 VGPRs
typedef __attribute__((ext_vector_type(8))) unsigned short u16x8;
typedef __attribute__((ext_vector_type(4))) float f32x4;

static __device__ __forceinline__ unsigned short f2bf(float f){
  unsigned u = __float_as_uint(f);
  u += 0x7fffu + ((u >> 16) & 1u);          // RNE
  return (unsigned short)(u >> 16);
}
static __device__ __forceinline__ float bf2f(unsigned short h){
  return __uint_as_float(((unsigned)h) << 16);
}

// ---------- merged weight PACK (f32 [K][N] -> bf16 frag-packed) + query pack ----------
// grid 5896: Wps 2048 | Wpt 1088 | Wos 2048 | Wot 512 | qconv 200
__global__ __launch_bounds__(256) void k_wtrans_all(
    const float* __restrict__ Wps, const float* __restrict__ Wpt,
    const float* __restrict__ Wos, const float* __restrict__ Wot,
    unsigned short* __restrict__ WpsP, unsigned short* __restrict__ WptP,
    unsigned short* __restrict__ WosP, unsigned short* __restrict__ WotP,
    const float4* __restrict__ qs, const float4* __restrict__ qt,
    unsigned short* __restrict__ qsP, unsigned short* __restrict__ qtP){
  int id = blockIdx.x;
  if(id >= 5696){
    // query bf16 conversion + fragment pack ([400][256] -> [25][8][64][8])
    int blk = id - 5696;
    const float4* in; unsigned short* out; int i;
    if(blk < 100){ in = qs; out = qsP; i = blk*256 + threadIdx.x; }
    else         { in = qt; out = qtP; i = (blk-100)*256 + threadIdx.x; }
    float4 v = in[i];
    int row = i >> 6, k0 = (i & 63) * 4;
    int strip = row >> 4, colr = row & 15;
    int kk = k0 >> 5, kg = (k0 >> 3) & 3, e0 = k0 & 7;
    size_t dst = ((size_t)(strip*8 + kk)*64 + kg*16 + colr)*8 + e0;
    *(ushort4*)(out + dst) = make_ushort4(f2bf(v.x), f2bf(v.y), f2bf(v.z), f2bf(v.w));
    return;
  }
  const float* in; unsigned short* out; int N, KKtot, r0, c0;
  if(id < 2048){       in=Wps; out=WpsP; N=32768; KKtot=8;    c0=(id>>2)*64;        r0=(id&3)*64; }
  else if(id < 3136){ int i=id-2048; in=Wpt; out=WptP; N=17408; KKtot=8;    c0=(i>>2)*64; r0=(i&3)*64; }
  else if(id < 5184){ int i=id-3136; in=Wos; out=WosP; N=256;   KKtot=1024; c0=(i&3)*64;  r0=(i>>2)*64; }
  else {              int i=id-5184; in=Wot; out=WotP; N=256;   KKtot=256;  c0=(i&3)*64;  r0=(i>>2)*64; }
  __shared__ float tile[64][65];          // [k-local][n-local]
  int lane = threadIdx.x & 63, wid = threadIdx.x >> 6;
  #pragma unroll
  for(int i=0;i<16;i++){
    int r = wid + 4*i;
    tile[r][lane] = in[(size_t)(r0 + r) * N + c0 + lane];
  }
  __syncthreads();
  int t = threadIdx.x;
  int ch = t >> 5, w2 = t & 31;
  int kk_l = ch >> 2, st_l = ch & 3;
  size_t chunkbase = ((size_t)((c0>>4) + st_l) * KKtot + ((r0>>5) + kk_l)) * 512;
  #pragma unroll
  for(int j=0;j<2;j++){
    int pl = w2*2 + j;
    int kg = pl >> 4, cc = pl & 15;
    u16x8 v;
    #pragma unroll
    for(int e=0;e<8;e++) v[e] = f2bf(tile[kk_l*32 + kg*8 + e][st_l*16 + cc]);
    *(u16x8*)(out + chunkbase + pl*8) = v;
  }
}

// ---------- merged feat transposes (B,256,8,P) f32 -> (B,P,8,256) bf16 ----------
// grid (85, 4, 32), vectorized: float4 loads, ushort4 stores
__global__ __launch_bounds__(256) void k_feat_transpose_all(
    const float* __restrict__ f0, const float* __restrict__ f1,
    const float* __restrict__ f2, const float* __restrict__ f3,
    unsigned short* __restrict__ o0, unsigned short* __restrict__ o1,
    unsigned short* __restrict__ o2, unsigned short* __restrict__ o3){
  int px = blockIdx.x;
  const float* in; unsigned short* out; int P, p0;
  if(px < 64){      in=f0; out=o0; P=4096; p0=px*64; }
  else if(px < 80){ in=f1; out=o1; P=1024; p0=(px-64)*64; }
  else if(px < 84){ in=f2; out=o2; P=256;  p0=(px-80)*64; }
  else {            in=f3; out=o3; P=64;   p0=0; }
  __shared__ float tile[64][65];              // [c][p]
  int c0 = blockIdx.y * 64;
  int b = blockIdx.z >> 3, t = blockIdx.z & 7;
  int tid = threadIdx.x;
  size_t inbase = ((size_t)b * 2048 + t) * (size_t)P;
  #pragma unroll
  for(int j=0;j<4;j++){
    int idx = j*256 + tid;
    int c = idx >> 4, q4 = idx & 15;
    float4 v = *(const float4*)(in + inbase + (size_t)(c0 + c) * 8 * P + p0 + q4*4);
    tile[c][q4*4+0] = v.x; tile[c][q4*4+1] = v.y;
    tile[c][q4*4+2] = v.z; tile[c][q4*4+3] = v.w;
  }
  __syncthreads();
  size_t outbase = (size_t)b * P * 2048 + (size_t)t * 256;
  #pragma unroll
  for(int j=0;j<4;j++){
    int idx = j*256 + tid;
    int p = idx >> 4, q4 = idx & 15;
    ushort4 o;
    o.x = f2bf(tile[q4*4+0][p]); o.y = f2bf(tile[q4*4+1][p]);
    o.z = f2bf(tile[q4*4+2][p]); o.w = f2bf(tile[q4*4+3][p]);
    *(ushort4*)(out + outbase + (size_t)(p0 + p) * 2048 + c0 + q4*4) = o;
  }
}

// ---------- offsets -> sample coords -> TAP TABLE (global, scalar-load-ready) ----------
// grid 400 (= B*Q), block 384.
// tapbuf[(bq*128 + point)*16 + l*4 + tap] = {arena_byte_off, weight_bits}
__global__ __launch_bounds__(384) void k_offsets(
    const float* __restrict__ q, const float* __restrict__ Woff,
    const float* __restrict__ boff, const float* __restrict__ boxes,
    int2* __restrict__ tapbuf){
  int bq = blockIdx.x;
  __shared__ float qsh[256];
  __shared__ float off[384];
  int tid = threadIdx.x;
  if(tid < 256) qsh[tid] = q[bq*256 + tid];
  __syncthreads();
  float acc = boff[tid];
  for(int k=0;k<256;k++) acc = fmaf(qsh[k], Woff[k*384 + tid], acc);
  off[tid] = acc;
  __syncthreads();
  if(tid < 128){
    float cx = boxes[bq*4+0], cy = boxes[bq*4+1];
    float zb = boxes[bq*4+2], r  = boxes[bq*4+3];
    float wx = exp2f(zb - 0.5f*r);
    float wy = exp2f(zb + 0.5f*r);
    float x = cx + off[tid*3+0]*wx;
    float y = cy + off[tid*3+1]*wy;
    float z = zb + off[tid*3+2];
    float m = z - 2.0f;                       // z - log2(stride0=4)
    float e0 = -0.5f*(m-0.f)*(m-0.f);         // /TAU, TAU=2
    float e1 = -0.5f*(m-1.f)*(m-1.f);
    float e2 = -0.5f*(m-2.f)*(m-2.f);
    float e3 = -0.5f*(m-3.f)*(m-3.f);
    float mx = fmaxf(fmaxf(e0,e1), fmaxf(e2,e3));
    float s0 = expf(e0-mx), s1 = expf(e1-mx), s2 = expf(e2-mx), s3 = expf(e3-mx);
    float inv = 1.0f/(s0+s1+s2+s3);
    float lwv[4] = {s0*inv, s1*inv, s2*inv, s3*inv};
    // arena layout (bytes from featT0): level bases + per-batch strides
    const int abase[4] = {0, 67108864, 83886080, 88080384};
    const int bsize[4] = {16777216, 4194304, 1048576, 262144};
    int b = bq / 100;
    int2* tp = tapbuf + ((size_t)bq*128 + tid)*16;
    #pragma unroll
    for(int l=0;l<4;l++){
      float invs = (l==0) ? 0.25f : (l==1) ? 0.125f : (l==2) ? 0.0625f : 0.03125f;
      int W = 64 >> l;
      float px = x*invs - 0.5f, py = y*invs - 0.5f;
      float x0f = floorf(px), y0f = floorf(py);
      int x0 = (int)x0f, y0 = (int)y0f;
      float fx = px - x0f, fy = py - y0f;
      int lb = abase[l] + b*bsize[l];
      #pragma unroll
      for(int tap=0; tap<4; tap++){
        int dx = tap & 1, dy = tap >> 1;
        int xi = x0 + dx, yi = y0 + dy;
        bool valid = (xi >= 0) & (xi < W) & (yi >= 0) & (yi < W);
        int xc = min(max(xi, 0), W-1), yc = min(max(yi, 0), W-1);
        float w = (dx ? fx : 1.f-fx) * (dy ? fy : 1.f-fy) * lwv[l];
        tp[l*4 + tap] = make_int2(lb + (yc*W + xc)*4096,
                                  __float_as_int(valid ? w : 0.f));
      }
    }
  }
}

// ---------- MERGED: bilinear sampling + means  ||  params GEMMs ----------
// grid 5520: [0,1600) sample blocks; [1600,5520) params blocks.
__global__ __launch_bounds__(256, 4) void k_sample_params(
    const unsigned short* __restrict__ arena,      // featT0 (= ws base of feat arena)
    const int2* __restrict__ tapbuf,
    float* __restrict__ sfeat, float* __restrict__ tfeat,
    const unsigned short* __restrict__ As, const unsigned short* __restrict__ WTs,
    const float* __restrict__ biass, unsigned short* __restrict__ outs,
    const unsigned short* __restrict__ At, const unsigned short* __restrict__ WTt,
    const float* __restrict__ biast, unsigned short* __restrict__ outt){
  if(blockIdx.x >= 1600){
    // ---------------- params GEMM branch (frag-packed operands) ----------------
    int flat = blockIdx.x - 1600;              // 0..3919
    int nb = flat % 784, my = flat / 784;      // nb: n-block, my: m-quintile
    const unsigned short *A, *W; const float* bias; unsigned short* out; int N, nbl;
    if(nb < 512){ A=As; W=WTs; bias=biass; out=outs; N=32768; nbl=nb; }
    else        { A=At; W=WTt; bias=biast; out=outt; N=17408; nbl=nb-512; }
    int wave = threadIdx.x >> 6, lane = threadIdx.x & 63;
    int strip = nbl*4 + wave;                  // n-strip of 16
    int col = lane & 15, kg = lane >> 4;
    const bf16x8* wp = (const bf16x8*)W + (size_t)strip*8*64 + lane;
    bf16x8 bfrag[8];
    #pragma unroll
    for(int k=0;k<8;k++) bfrag[k] = wp[k*64];  // contiguous 1KB wave-loads
    float bv = bias[strip*16 + col];
    int mt0 = my * 5;
    #pragma unroll
    for(int m=0; m<5; m++){
      int mt = mt0 + m;
      f32x4 acc = {bv, bv, bv, bv};
      const bf16x8* ap = (const bf16x8*)A + (size_t)mt*8*64 + lane;
      bf16x8 af[8];
      #pragma unroll
      for(int k=0;k<8;k++) af[k] = ap[k*64];
      #pragma unroll
      for(int k=0;k<8;k++)
        acc = __builtin_amdgcn_mfma_f32_16x16x32_bf16(af[k], bfrag[k], acc, 0, 0, 0);
      int rowb = mt*16 + kg*4;
      #pragma unroll
      for(int r=0;r<4;r++)
        out[(size_t)(rowb + r) * N + strip*16 + col] = f2bf(acc[r]);
    }
    return;
  }
  // ---------------- sampling branch: taps from SGPRs (uniform loads) ----------------
  int bid = blockIdx.x;
  int g = bid & 3, bq = bid >> 2;
  __shared__ unsigned smp[32][8][32];         // packed 2xbf16, 32 KB
  int tid = threadIdx.x;
  int cp = tid & 31, t = tid >> 5;
  int tcb = t*512 + g*128 + cp*4;             // per-thread byte offset (const across taps)
  const char* ar = (const char*)arena;
  const int2* tb = tapbuf + (size_t)(bq*128 + g*32)*16;   // wave-uniform base
  float t0 = 0.f, t1 = 0.f;
  #pragma unroll 2
  for(int sp=0; sp<32; sp++){
    float a0 = 0.f, a1 = 0.f;
    #pragma unroll
    for(int j=0; j<16; j++){
      int2 td = tb[sp*16 + j];                // uniform addr -> s_load -> SGPRs
      float w = __int_as_float(td.y);
      unsigned v = *(const unsigned*)(ar + (size_t)(unsigned)td.x + tcb);
      a0 = fmaf(w, __uint_as_float((v & 0xffffu) << 16), a0);
      a1 = fmaf(w, __uint_as_float(v & 0xffff0000u),      a1);
    }
    smp[sp][t][cp] = (unsigned)f2bf(a0) | ((unsigned)f2bf(a1) << 16);
    t0 += a0; t1 += a1;
  }
  __syncthreads();
  // temporal mean over SP=32 (f32-accumulated in registers)
  {
    size_t o = ((size_t)(bq*4 + g)*8 + t)*64 + cp*2;
    tfeat[o+0] = t0 * (1.f/32.f);
    tfeat[o+1] = t1 * (1.f/32.f);
  }
  // spatial mean over T=8 : 32 sp x 32 pairs, 4 per thread
  #pragma unroll
  for(int i=0;i<4;i++){
    int j = tid + 256*i;
    int sp = j >> 5, p = j & 31;
    float s0 = 0.f, s1 = 0.f;
    #pragma unroll
    for(int tt=0; tt<8; tt++){
      unsigned v = smp[sp][tt][p];
      s0 += __uint_as_float((v & 0xffffu) << 16);
      s1 += __uint_as_float(v & 0xffff0000u);
    }
    size_t o = ((size_t)(bq*4 + g)*32 + sp)*64 + p*2;
    sfeat[o+0] = s0 * 0.125f;
    sfeat[o+1] = s1 * 0.125f;
  }
}

// ---------- block reduce (sum, sumsq) over 256 threads ----------
static __device__ __forceinline__ void block_reduce2(
    float& s1, float& s2, float* rA, float* rB, int tid){
  #pragma unroll
  for(int o=32;o;o>>=1){ s1 += __shfl_xor(s1,o); s2 += __shfl_xor(s2,o); }
  int wave = tid >> 6, lane = tid & 63;
  if(lane == 0){ rA[wave] = s1; rB[wave] = s2; }
  __syncthreads();
  s1 = rA[0]+rA[1]+rA[2]+rA[3];
  s2 = rB[0]+rB[1]+rB[2]+rB[3];
}

// ---------- adaptive mixing body (bf16 params, frag-packed hid write) ----------
template<int P, int O>
static __device__ void mix_body(
    float* shbuf, const float* __restrict__ feats,
    const unsigned short* __restrict__ params,
    unsigned short* __restrict__ hidden, int KK, int bid){
  int g = bid & 3, bq = bid >> 2;
  const int PG = 4096 + O*P;
  const unsigned short* pp = params + (size_t)bq * 4 * PG + (size_t)g * PG;
  const float* xin = feats + (size_t)(bq*4 + g) * P * 64;
  float (*xs)[64] = (float(*)[64])shbuf;
  float (*o1)[64] = (float(*)[64])(shbuf + P*64);
  float* Ss = shbuf + 2*P*64;
  float* rA = shbuf + 2*P*64 + O*P;
  float* rB = rA + 4;
  int tid = threadIdx.x; int d = tid & 63; int pb = tid >> 6;
  for(int i=tid; i<P*64; i+=256) xs[i>>6][i&63] = xin[i];
  for(int i=tid; i<O*P; i+=256) Ss[i] = bf2f(pp[4096 + i]);
  __syncthreads();
  constexpr int NP = P/4;
  float a[NP];
  #pragma unroll
  for(int i=0;i<NP;i++) a[i] = 0.f;
  for(int c=0;c<64;c++){
    float mv = bf2f(pp[c*64 + d]);
    #pragma unroll
    for(int i=0;i<NP;i++) a[i] = fmaf(xs[pb + 4*i][c], mv, a[i]);
  }
  float s1 = 0.f, s2 = 0.f;
  #pragma unroll
  for(int i=0;i<NP;i++){ s1 += a[i]; s2 += a[i]*a[i]; }
  block_reduce2(s1, s2, rA, rB, tid);
  {
    const float n = (float)(P*64);
    float mu = s1/n, var = s2/n - mu*mu;
    float rstd = rsqrtf(var + 1e-5f);
    #pragma unroll
    for(int i=0;i<NP;i++){
      float v = (a[i] - mu) * rstd;
      o1[pb + 4*i][d] = fmaxf(v, 0.f);
    }
  }
  __syncthreads();
  constexpr int NO = O/4;
  float bacc[NO];
  #pragma unroll
  for(int i=0;i<NO;i++){
    float acc = 0.f;
    int o = pb + 4*i;
    #pragma unroll
    for(int p=0;p<P;p++) acc = fmaf(Ss[o*P + p], o1[p][d], acc);
    bacc[i] = acc;
  }
  s1 = 0.f; s2 = 0.f;
  #pragma unroll
  for(int i=0;i<NO;i++){ s1 += bacc[i]; s2 += bacc[i]*bacc[i]; }
  block_reduce2(s1, s2, rA, rB, tid);
  {
    const float n = (float)(O*64);
    float mu = s1/n, var = s2/n - mu*mu;
    float rstd = rsqrtf(var + 1e-5f);
    int strip = bq >> 4, colr = bq & 15;
    int kg = (d >> 3) & 3, e = d & 7, dh = d >> 5;
    #pragma unroll
    for(int i=0;i<NO;i++){
      int o = pb + 4*i;
      float v = (bacc[i] - mu) * rstd;
      int kk = (g*O + o)*2 + dh;
      size_t addr = ((size_t)(strip*KK + kk)*64 + kg*16 + colr)*8 + e;
      hidden[addr] = f2bf(fmaxf(v, 0.f));
    }
  }
}

// ---------- merged mixing: grid 3200 ([0,1600) spatial, [1600,3200) temporal) ----------
__global__ __launch_bounds__(256) void k_mix_all(
    const float* __restrict__ sfeat, const unsigned short* __restrict__ params_s,
    unsigned short* __restrict__ hid_s,
    const float* __restrict__ tfeat, const unsigned short* __restrict__ params_t,
    unsigned short* __restrict__ hid_t){
  __shared__ float shbuf[2*32*64 + 128*32 + 8];    // 32.8 KB (spatial worst case)
  if(blockIdx.x < 1600)
    mix_body<32,128>(shbuf, sfeat, params_s, hid_s, 1024, blockIdx.x);
  else
    mix_body<8,32>(shbuf, tfeat, params_t, hid_t, 256, blockIdx.x - 1600);
}

// ---------- merged final GEMMs (frag-packed): partial[32][400][256] each ----------
// grid (64, 25): bx<32 -> spatial slab, else temporal slab.
__global__ __launch_bounds__(256, 4) void k_gemm_final(
    const unsigned short* __restrict__ Hs, const unsigned short* __restrict__ WTs,
    float* __restrict__ parts, const unsigned short* __restrict__ Ht,
    const unsigned short* __restrict__ WTt, float* __restrict__ partt){
  const unsigned short *H, *W; float* partial; int KK, ks, ksteps;
  if(blockIdx.x < 32){ H=Hs; W=WTs; partial=parts; KK=1024; ks=blockIdx.x;    ksteps=32; }
  else               { H=Ht; W=WTt; partial=partt; KK=256;  ks=blockIdx.x-32; ksteps=8;  }
  int wave = threadIdx.x >> 6, lane = threadIdx.x & 63;
  int col = lane & 15, kg = lane >> 4;
  int mt = blockIdx.y;
  int kk0 = ks * ksteps;
  int n0 = wave * 64;
  f32x4 acc[4] = {};
  const bf16x8* ap  = (const bf16x8*)H + ((size_t)mt*KK + kk0)*64 + lane;
  const bf16x8* bp0 = (const bf16x8*)W + ((size_t)(4*wave+0)*KK + kk0)*64 + lane;
  const bf16x8* bp1 = (const bf16x8*)W + ((size_t)(4*wave+1)*KK + kk0)*64 + lane;
  const bf16x8* bp2 = (const bf16x8*)W + ((size_t)(4*wave+2)*KK + kk0)*64 + lane;
  const bf16x8* bp3 = (const bf16x8*)W + ((size_t)(4*wave+3)*KK + kk0)*64 + lane;
  #pragma unroll 4
  for(int kk=0; kk<ksteps; kk++){
    bf16x8 af = ap[kk*64];
    bf16x8 b0 = bp0[kk*64], b1 = bp1[kk*64], b2 = bp2[kk*64], b3 = bp3[kk*64];
    acc[0] = __builtin_amdgcn_mfma_f32_16x16x32_bf16(af, b0, acc[0], 0,0,0);
    acc[1] = __builtin_amdgcn_mfma_f32_16x16x32_bf16(af, b1, acc[1], 0,0,0);
    acc[2] = __builtin_amdgcn_mfma_f32_16x16x32_bf16(af, b2, acc[2], 0,0,0);
    acc[3] = __builtin_amdgcn_mfma_f32_16x16x32_bf16(af, b3, acc[3], 0,0,0);
  }
  int rowb = mt*16 + kg*4;
  #pragma unroll
  for(int nt=0; nt<4; nt++)
    #pragma unroll
    for(int r=0; r<4; r++)
      partial[((size_t)ks*400 + rowb + r)*256 + n0 + nt*16 + col] = acc[nt][r];
}

// ---------- finalize both outputs: residual + bias + LN -> out ----------
// grid (400, 2), block 256
template<int NS>
__global__ __launch_bounds__(256) void k_finalize(
    const float* __restrict__ part_s, const float* __restrict__ part_t,
    const float* __restrict__ qs, const float* __restrict__ qt,
    const float* __restrict__ bos, const float* __restrict__ bot,
    const float* __restrict__ gs, const float* __restrict__ gt,
    const float* __restrict__ bes, const float* __restrict__ bet,
    float* __restrict__ out_s, float* __restrict__ out_t){
  __shared__ float rA[4], rB[4];
  int bq = blockIdx.x, j = threadIdx.x;
  const float *partial, *q, *bo, *gam, *bet_;
  float* out;
  if(blockIdx.y == 0){ partial=part_s; q=qs; bo=bos; gam=gs; bet_=bes; out=out_s; }
  else               { partial=part_t; q=qt; bo=bot; gam=gt; bet_=bet; out=out_t; }
  float v = q[bq*256 + j] + bo[j];
  #pragma unroll 8
  for(int s=0;s<NS;s++) v += partial[((size_t)s*400 + bq)*256 + j];
  float s1 = v, s2 = v*v;
  block_reduce2(s1, s2, rA, rB, j);
  float mu = s1 * (1.f/256.f);
  float var = s2 * (1.f/256.f) - mu*mu;
  float rstd = rsqrtf(var + 1e-5f);
  out[bq*256 + j] = (v - mu) * rstd * gam[j] + bet_[j];
}

// ---------------------------------------------------------------------------
extern "C" void kernel_launch(void* const* d_in, const int* in_sizes, int n_in,
                              void* d_out, int out_size, void* d_ws, size_t ws_size,
                              hipStream_t stream){
  const float* feat0 = (const float*)d_in[0];
  const float* feat1 = (const float*)d_in[1];
  const float* feat2 = (const float*)d_in[2];
  const float* feat3 = (const float*)d_in[3];
  const float* boxes = (const float*)d_in[4];
  const float* qs    = (const float*)d_in[5];
  const float* qt    = (const float*)d_in[6];
  const float* Woff  = (const float*)d_in[7];
  const float* boff  = (const float*)d_in[8];
  const float* Wps   = (const float*)d_in[9];
  const float* bps   = (const float*)d_in[10];
  const float* Wos   = (const float*)d_in[11];
  const float* bos   = (const float*)d_in[12];
  const float* gs    = (const float*)d_in[13];
  const float* bes   = (const float*)d_in[14];
  const float* Wpt   = (const float*)d_in[15];
  const float* bpt   = (const float*)d_in[16];
  const float* Wot   = (const float*)d_in[17];
  const float* bot   = (const float*)d_in[18];
  const float* gt    = (const float*)d_in[19];
  const float* bet   = (const float*)d_in[20];

  char* ws = (char*)d_ws;
  // featT arena (offsets baked into tapbuf): featT0 MUST stay at ws+0 with
  // featT1/2/3 at the fixed offsets below. Dead after sample -> partials alias.
  unsigned short* featT0 = (unsigned short*)(ws + 0);
  unsigned short* featT1 = (unsigned short*)(ws + 67108864);
  unsigned short* featT2 = (unsigned short*)(ws + 83886080);
  unsigned short* featT3 = (unsigned short*)(ws + 88080384);
  float* part_s          = (float*)(ws + 0);            // 13,107,200 B (NS=32)
  float* part_t          = (float*)(ws + 52428800);     // 13,107,200 B
  unsigned short* qsP    = (unsigned short*)(ws + 89128960);    //   204,800
  unsigned short* qtP    = (unsigned short*)(ws + 89333760);    //   204,800
  unsigned short* WpsP   = (unsigned short*)(ws + 89538560);    // 16,777,216
  unsigned short* WptP   = (unsigned short*)(ws + 106315776);   //  8,912,896
  unsigned short* WosP   = (unsigned short*)(ws + 115228672);   // 16,777,216
  unsigned short* WotP   = (unsigned short*)(ws + 132005888);   //  4,194,304
  float* sfeat           = (float*)(ws + 137461760);
  float* tfeat           = (float*)(ws + 150568960);
  unsigned short* hid_s  = (unsigned short*)(ws + 153845760);   // 26,214,400 (packed)
  unsigned short* hid_t  = (unsigned short*)(ws + 180060160);   //  6,553,600 (packed)
  unsigned short* params_s = (unsigned short*)(ws + 186613760); // 26,214,400 (bf16)
  unsigned short* params_t = (unsigned short*)(ws + 212828160); // 13,926,400 (bf16)
  int2* tapbuf           = (int2*)(ws + 226754560);             //  6,553,600
  float* out_s = (float*)d_out;
  float* out_t = out_s + 102400;

  // 1. weight frag-packs + query pack (own regalloc)
  k_wtrans_all<<<5896, 256, 0, stream>>>(Wps, Wpt, Wos, Wot, WpsP, WptP, WosP, WotP,
                                         (const float4*)qs, (const float4*)qt, qsP, qtP);
  // 2. feature transposes (own regalloc, vectorized)
  k_feat_transpose_all<<<dim3(85, 4, 32), 256, 0, stream>>>(
      feat0, feat1, feat2, feat3, featT0, featT1, featT2, featT3);
  // 3. offsets -> tap table
  k_offsets<<<400, 384, 0, stream>>>(qs, Woff, boff, boxes, tapbuf);
  // 4. sampling + params GEMMs in ONE launch (independent; overlap)
  k_sample_params<<<5520, 256, 0, stream>>>(featT0, tapbuf, sfeat, tfeat,
                                            qsP, WpsP, bps, params_s,
                                            qtP, WptP, bpt, params_t);
  // 5. adaptive mixing (merged s+t; hid written frag-packed)
  k_mix_all<<<3200, 256, 0, stream>>>(sfeat, params_s, hid_s,
                                      tfeat, params_t, hid_t);
  // 6. final GEMMs (NS=32; partials alias dead featT region)
  k_gemm_final<<<dim3(64, 25), 256, 0, stream>>>(hid_s, WosP, part_s,
                                                 hid_t, WotP, part_t);
  // 7. finalize (merged)
  k_finalize<32><<<dim3(400, 2), 256, 0, stream>>>(
      part_s, part_t, qs, qt, bos, bot, gs, gt, bes, bet, out_s, out_t);
}

// Round 17
// 267.053 us; speedup vs baseline: 1.0706x; 1.0706x over previous
//
#include <hip/hip_runtime.h>
#include <hip/hip_bf16.h>

// ---------------------------------------------------------------------------
// AdaptiveSTSamplingMixing — MI355X implementation
// R16: (1) k_prep = wtrans+ftrans+qconv in ONE launch with
//      __launch_bounds__(256,4) (R11 retro-diagnosis: mega-merge failed for
//      lack of a VGPR floor, not heterogeneity). (2) arena re-laid out as
//      [l][g][b][p][t][c64] -> tap row 1024B contiguous, 256B/wave-load
//      segments (traffic-neutral; enables fp8 flip next round).
//      Sample branch confirmed L3-BW-bound (~9.7 TB/s) — not touched further.
// ---------------------------------------------------------------------------

typedef __attribute__((ext_vector_type(8))) short bf16x8;   // 8 bf16 in 4 VGPRs
typedef __attribute__((ext_vector_type(8))) unsigned short u16x8;
typedef __attribute__((ext_vector_type(4))) float f32x4;

static __device__ __forceinline__ unsigned short f2bf(float f){
  unsigned u = __float_as_uint(f);
  u += 0x7fffu + ((u >> 16) & 1u);          // RNE
  return (unsigned short)(u >> 16);
}
static __device__ __forceinline__ float bf2f(unsigned short h){
  return __uint_as_float(((unsigned)h) << 16);
}

// ---------- PREP: feat transposes + weight frag-packs + query pack ----------
// grid 16776: ftrans [0,10880) | wtrans [10880,16576) | qconv [16576,16776)
// ftrans out layout: arena[l][g][b][p][t][c64] (ushort units):
//   base_us = {0, 33554432, 41943040, 44040192}; gsize_us = {8388608,2097152,524288,131072}
__global__ __launch_bounds__(256, 4) void k_prep(
    const float* __restrict__ f0, const float* __restrict__ f1,
    const float* __restrict__ f2, const float* __restrict__ f3,
    unsigned short* __restrict__ arena,
    const float* __restrict__ Wps, const float* __restrict__ Wpt,
    const float* __restrict__ Wos, const float* __restrict__ Wot,
    unsigned short* __restrict__ WpsP, unsigned short* __restrict__ WptP,
    unsigned short* __restrict__ WosP, unsigned short* __restrict__ WotP,
    const float4* __restrict__ qs4, const float4* __restrict__ qt4,
    unsigned short* __restrict__ qsP, unsigned short* __restrict__ qtP){
  __shared__ float tile[64][65];
  int id = blockIdx.x;
  int tid = threadIdx.x;

  if(id < 10880){
    // ---------------- feat transpose (vectorized, per-g output) ----------------
    int px = id % 85, rest = id / 85;          // rest in [0,128)
    int g = rest & 3;
    int z = rest >> 2;                         // [0,32)
    int b = z >> 3, t = z & 7;
    const float* in; int P, p0, l;
    if(px < 64){      in=f0; P=4096; p0=px*64;      l=0; }
    else if(px < 80){ in=f1; P=1024; p0=(px-64)*64; l=1; }
    else if(px < 84){ in=f2; P=256;  p0=(px-80)*64; l=2; }
    else {            in=f3; P=64;   p0=0;          l=3; }
    const size_t base_us[4]  = {0, 33554432, 41943040, 44040192};
    const size_t gsize_us[4] = {8388608, 2097152, 524288, 131072};
    int c0 = g*64;
    size_t inbase = ((size_t)b * 2048 + t) * (size_t)P;
    #pragma unroll
    for(int j=0;j<4;j++){
      int idx = j*256 + tid;
      int c = idx >> 4, q4 = idx & 15;
      float4 v = *(const float4*)(in + inbase + (size_t)(c0 + c) * 8 * P + p0 + q4*4);
      tile[c][q4*4+0] = v.x; tile[c][q4*4+1] = v.y;
      tile[c][q4*4+2] = v.z; tile[c][q4*4+3] = v.w;
    }
    __syncthreads();
    unsigned short* out = arena + base_us[l] + g*gsize_us[l];
    #pragma unroll
    for(int j=0;j<4;j++){
      int idx = j*256 + tid;
      int p = idx >> 4, q4 = idx & 15;
      ushort4 o;
      o.x = f2bf(tile[q4*4+0][p]); o.y = f2bf(tile[q4*4+1][p]);
      o.z = f2bf(tile[q4*4+2][p]); o.w = f2bf(tile[q4*4+3][p]);
      *(ushort4*)(out + ((size_t)(b*P + p0 + p)*8 + t)*64 + q4*4) = o;
    }
    return;
  }

  if(id < 16576){
    // ---------------- weight frag-pack ----------------
    int wi = id - 10880;                       // [0,5696)
    const float* in; unsigned short* out; int N, KKtot, r0, c0;
    if(wi < 2048){       in=Wps; out=WpsP; N=32768; KKtot=8;    c0=(wi>>2)*64;        r0=(wi&3)*64; }
    else if(wi < 3136){ int i2=wi-2048; in=Wpt; out=WptP; N=17408; KKtot=8;    c0=(i2>>2)*64; r0=(i2&3)*64; }
    else if(wi < 5184){ int i2=wi-3136; in=Wos; out=WosP; N=256;   KKtot=1024; c0=(i2&3)*64;  r0=(i2>>2)*64; }
    else {              int i2=wi-5184; in=Wot; out=WotP; N=256;   KKtot=256;  c0=(i2&3)*64;  r0=(i2>>2)*64; }
    int lane = tid & 63, wid = tid >> 6;
    #pragma unroll
    for(int i2=0;i2<16;i2++){
      int r = wid + 4*i2;
      tile[r][lane] = in[(size_t)(r0 + r) * N + c0 + lane];
    }
    __syncthreads();
    int ch = tid >> 5, w2 = tid & 31;
    int kk_l = ch >> 2, st_l = ch & 3;
    size_t chunkbase = ((size_t)((c0>>4) + st_l) * KKtot + ((r0>>5) + kk_l)) * 512;
    #pragma unroll
    for(int j=0;j<2;j++){
      int pl = w2*2 + j;
      int kg = pl >> 4, cc = pl & 15;
      u16x8 v;
      #pragma unroll
      for(int e=0;e<8;e++) v[e] = f2bf(tile[kk_l*32 + kg*8 + e][st_l*16 + cc]);
      *(u16x8*)(out + chunkbase + pl*8) = v;
    }
    return;
  }

  // ---------------- query bf16 conversion + fragment pack ----------------
  {
    int blk = id - 16576;
    const float4* in; unsigned short* out; int i;
    if(blk < 100){ in = qs4; out = qsP; i = blk*256 + tid; }
    else         { in = qt4; out = qtP; i = (blk-100)*256 + tid; }
    float4 v = in[i];
    int row = i >> 6, k0 = (i & 63) * 4;
    int strip = row >> 4, colr = row & 15;
    int kk = k0 >> 5, kg = (k0 >> 3) & 3, e0 = k0 & 7;
    size_t dst = ((size_t)(strip*8 + kk)*64 + kg*16 + colr)*8 + e0;
    *(ushort4*)(out + dst) = make_ushort4(f2bf(v.x), f2bf(v.y), f2bf(v.z), f2bf(v.w));
  }
}

// ---------- offsets -> sample coords -> TAP TABLE ----------
// grid 400 (= B*Q), block 384.
// tapbuf[(bq*128 + point)*16 + l*4 + tap] = {arena_byte_off, weight_bits}
// arena_byte_off = lbase + g*gsize + b*bsize + (y*W+x)*1024 (per-g layout).
__global__ __launch_bounds__(384) void k_offsets(
    const float* __restrict__ q, const float* __restrict__ Woff,
    const float* __restrict__ boff, const float* __restrict__ boxes,
    int2* __restrict__ tapbuf){
  int bq = blockIdx.x;
  __shared__ float qsh[256];
  __shared__ float off[384];
  int tid = threadIdx.x;
  if(tid < 256) qsh[tid] = q[bq*256 + tid];
  __syncthreads();
  float acc = boff[tid];
  for(int k=0;k<256;k++) acc = fmaf(qsh[k], Woff[k*384 + tid], acc);
  off[tid] = acc;
  __syncthreads();
  if(tid < 128){
    float cx = boxes[bq*4+0], cy = boxes[bq*4+1];
    float zb = boxes[bq*4+2], r  = boxes[bq*4+3];
    float wx = exp2f(zb - 0.5f*r);
    float wy = exp2f(zb + 0.5f*r);
    float x = cx + off[tid*3+0]*wx;
    float y = cy + off[tid*3+1]*wy;
    float z = zb + off[tid*3+2];
    float m = z - 2.0f;                       // z - log2(stride0=4)
    float e0 = -0.5f*(m-0.f)*(m-0.f);         // /TAU, TAU=2
    float e1 = -0.5f*(m-1.f)*(m-1.f);
    float e2 = -0.5f*(m-2.f)*(m-2.f);
    float e3 = -0.5f*(m-3.f)*(m-3.f);
    float mx = fmaxf(fmaxf(e0,e1), fmaxf(e2,e3));
    float s0 = expf(e0-mx), s1 = expf(e1-mx), s2 = expf(e2-mx), s3 = expf(e3-mx);
    float inv = 1.0f/(s0+s1+s2+s3);
    float lwv[4] = {s0*inv, s1*inv, s2*inv, s3*inv};
    // per-g arena (bytes): level base, per-g size, per-b size
    const int abase[4] = {0, 67108864, 83886080, 88080384};
    const int gsize[4] = {16777216, 4194304, 1048576, 262144};
    const int bsize[4] = {4194304, 1048576, 262144, 65536};
    int b = bq / 100;
    int g = tid >> 5;
    int2* tp = tapbuf + ((size_t)bq*128 + tid)*16;
    #pragma unroll
    for(int l=0;l<4;l++){
      float invs = (l==0) ? 0.25f : (l==1) ? 0.125f : (l==2) ? 0.0625f : 0.03125f;
      int W = 64 >> l;
      float px = x*invs - 0.5f, py = y*invs - 0.5f;
      float x0f = floorf(px), y0f = floorf(py);
      int x0 = (int)x0f, y0 = (int)y0f;
      float fx = px - x0f, fy = py - y0f;
      int lb = abase[l] + g*gsize[l] + b*bsize[l];
      #pragma unroll
      for(int tap=0; tap<4; tap++){
        int dx = tap & 1, dy = tap >> 1;
        int xi = x0 + dx, yi = y0 + dy;
        bool valid = (xi >= 0) & (xi < W) & (yi >= 0) & (yi < W);
        int xc = min(max(xi, 0), W-1), yc = min(max(yi, 0), W-1);
        float w = (dx ? fx : 1.f-fx) * (dy ? fy : 1.f-fy) * lwv[l];
        tp[l*4 + tap] = make_int2(lb + (yc*W + xc)*1024,
                                  __float_as_int(valid ? w : 0.f));
      }
    }
  }
}

// ---------- MERGED: bilinear sampling + means  ||  params GEMMs ----------
// grid 5520: [0,1600) sample blocks; [1600,5520) params blocks.
__global__ __launch_bounds__(256, 4) void k_sample_params(
    const unsigned short* __restrict__ arena,
    const int2* __restrict__ tapbuf,
    float* __restrict__ sfeat, float* __restrict__ tfeat,
    const unsigned short* __restrict__ As, const unsigned short* __restrict__ WTs,
    const float* __restrict__ biass, unsigned short* __restrict__ outs,
    const unsigned short* __restrict__ At, const unsigned short* __restrict__ WTt,
    const float* __restrict__ biast, unsigned short* __restrict__ outt){
  if(blockIdx.x >= 1600){
    // ---------------- params GEMM branch (frag-packed operands) ----------------
    int flat = blockIdx.x - 1600;              // 0..3919
    int nb = flat % 784, my = flat / 784;      // nb: n-block, my: m-quintile
    const unsigned short *A, *W; const float* bias; unsigned short* out; int N, nbl;
    if(nb < 512){ A=As; W=WTs; bias=biass; out=outs; N=32768; nbl=nb; }
    else        { A=At; W=WTt; bias=biast; out=outt; N=17408; nbl=nb-512; }
    int wave = threadIdx.x >> 6, lane = threadIdx.x & 63;
    int strip = nbl*4 + wave;                  // n-strip of 16
    int col = lane & 15, kg = lane >> 4;
    const bf16x8* wp = (const bf16x8*)W + (size_t)strip*8*64 + lane;
    bf16x8 bfrag[8];
    #pragma unroll
    for(int k=0;k<8;k++) bfrag[k] = wp[k*64];  // contiguous 1KB wave-loads
    float bv = bias[strip*16 + col];
    int mt0 = my * 5;
    #pragma unroll
    for(int m=0; m<5; m++){
      int mt = mt0 + m;
      f32x4 acc = {bv, bv, bv, bv};
      const bf16x8* ap = (const bf16x8*)A + (size_t)mt*8*64 + lane;
      bf16x8 af[8];
      #pragma unroll
      for(int k=0;k<8;k++) af[k] = ap[k*64];
      #pragma unroll
      for(int k=0;k<8;k++)
        acc = __builtin_amdgcn_mfma_f32_16x16x32_bf16(af[k], bfrag[k], acc, 0, 0, 0);
      int rowb = mt*16 + kg*4;
      #pragma unroll
      for(int r=0;r<4;r++)
        out[(size_t)(rowb + r) * N + strip*16 + col] = f2bf(acc[r]);
    }
    return;
  }
  // ---------------- sampling branch: per-g arena, scalar taps ----------------
  int bid = blockIdx.x;
  int g = bid & 3, bq = bid >> 2;
  __shared__ unsigned smp[32][8][32];         // packed 2xbf16, 32 KB
  int tid = threadIdx.x;
  int cp = tid & 31, t = tid >> 5;
  int tcb = t*128 + cp*4;                     // byte offset within 1024B tap row
  const char* ar = (const char*)arena;
  const int2* tb = tapbuf + (size_t)(bq*128 + g*32)*16;   // wave-uniform base
  float t0 = 0.f, t1 = 0.f;
  #pragma unroll 2
  for(int sp=0; sp<32; sp++){
    float a0 = 0.f, a1 = 0.f;
    #pragma unroll
    for(int j=0; j<16; j++){
      int2 td = tb[sp*16 + j];                // uniform addr -> s_load -> SGPRs
      float w = __int_as_float(td.y);
      unsigned v = *(const unsigned*)(ar + (size_t)(unsigned)td.x + tcb);
      a0 = fmaf(w, __uint_as_float((v & 0xffffu) << 16), a0);
      a1 = fmaf(w, __uint_as_float(v & 0xffff0000u),      a1);
    }
    smp[sp][t][cp] = (unsigned)f2bf(a0) | ((unsigned)f2bf(a1) << 16);
    t0 += a0; t1 += a1;
  }
  __syncthreads();
  // temporal mean over SP=32 (f32-accumulated in registers)
  {
    size_t o = ((size_t)(bq*4 + g)*8 + t)*64 + cp*2;
    tfeat[o+0] = t0 * (1.f/32.f);
    tfeat[o+1] = t1 * (1.f/32.f);
  }
  // spatial mean over T=8 : 32 sp x 32 pairs, 4 per thread
  #pragma unroll
  for(int i=0;i<4;i++){
    int j = tid + 256*i;
    int sp = j >> 5, p = j & 31;
    float s0 = 0.f, s1 = 0.f;
    #pragma unroll
    for(int tt=0; tt<8; tt++){
      unsigned v = smp[sp][tt][p];
      s0 += __uint_as_float((v & 0xffffu) << 16);
      s1 += __uint_as_float(v & 0xffff0000u);
    }
    size_t o = ((size_t)(bq*4 + g)*32 + sp)*64 + p*2;
    sfeat[o+0] = s0 * 0.125f;
    sfeat[o+1] = s1 * 0.125f;
  }
}

// ---------- block reduce (sum, sumsq) over 256 threads ----------
static __device__ __forceinline__ void block_reduce2(
    float& s1, float& s2, float* rA, float* rB, int tid){
  #pragma unroll
  for(int o=32;o;o>>=1){ s1 += __shfl_xor(s1,o); s2 += __shfl_xor(s2,o); }
  int wave = tid >> 6, lane = tid & 63;
  if(lane == 0){ rA[wave] = s1; rB[wave] = s2; }
  __syncthreads();
  s1 = rA[0]+rA[1]+rA[2]+rA[3];
  s2 = rB[0]+rB[1]+rB[2]+rB[3];
}

// ---------- adaptive mixing body (bf16 params, frag-packed hid write) ----------
template<int P, int O>
static __device__ void mix_body(
    float* shbuf, const float* __restrict__ feats,
    const unsigned short* __restrict__ params,
    unsigned short* __restrict__ hidden, int KK, int bid){
  int g = bid & 3, bq = bid >> 2;
  const int PG = 4096 + O*P;
  const unsigned short* pp = params + (size_t)bq * 4 * PG + (size_t)g * PG;
  const float* xin = feats + (size_t)(bq*4 + g) * P * 64;
  float (*xs)[64] = (float(*)[64])shbuf;
  float (*o1)[64] = (float(*)[64])(shbuf + P*64);
  float* Ss = shbuf + 2*P*64;
  float* rA = shbuf + 2*P*64 + O*P;
  float* rB = rA + 4;
  int tid = threadIdx.x; int d = tid & 63; int pb = tid >> 6;
  for(int i=tid; i<P*64; i+=256) xs[i>>6][i&63] = xin[i];
  for(int i=tid; i<O*P; i+=256) Ss[i] = bf2f(pp[4096 + i]);
  __syncthreads();
  constexpr int NP = P/4;
  float a[NP];
  #pragma unroll
  for(int i=0;i<NP;i++) a[i] = 0.f;
  for(int c=0;c<64;c++){
    float mv = bf2f(pp[c*64 + d]);
    #pragma unroll
    for(int i=0;i<NP;i++) a[i] = fmaf(xs[pb + 4*i][c], mv, a[i]);
  }
  float s1 = 0.f, s2 = 0.f;
  #pragma unroll
  for(int i=0;i<NP;i++){ s1 += a[i]; s2 += a[i]*a[i]; }
  block_reduce2(s1, s2, rA, rB, tid);
  {
    const float n = (float)(P*64);
    float mu = s1/n, var = s2/n - mu*mu;
    float rstd = rsqrtf(var + 1e-5f);
    #pragma unroll
    for(int i=0;i<NP;i++){
      float v = (a[i] - mu) * rstd;
      o1[pb + 4*i][d] = fmaxf(v, 0.f);
    }
  }
  __syncthreads();
  constexpr int NO = O/4;
  float bacc[NO];
  #pragma unroll
  for(int i=0;i<NO;i++){
    float acc = 0.f;
    int o = pb + 4*i;
    #pragma unroll
    for(int p=0;p<P;p++) acc = fmaf(Ss[o*P + p], o1[p][d], acc);
    bacc[i] = acc;
  }
  s1 = 0.f; s2 = 0.f;
  #pragma unroll
  for(int i=0;i<NO;i++){ s1 += bacc[i]; s2 += bacc[i]*bacc[i]; }
  block_reduce2(s1, s2, rA, rB, tid);
  {
    const float n = (float)(O*64);
    float mu = s1/n, var = s2/n - mu*mu;
    float rstd = rsqrtf(var + 1e-5f);
    int strip = bq >> 4, colr = bq & 15;
    int kg = (d >> 3) & 3, e = d & 7, dh = d >> 5;
    #pragma unroll
    for(int i=0;i<NO;i++){
      int o = pb + 4*i;
      float v = (bacc[i] - mu) * rstd;
      int kk = (g*O + o)*2 + dh;
      size_t addr = ((size_t)(strip*KK + kk)*64 + kg*16 + colr)*8 + e;
      hidden[addr] = f2bf(fmaxf(v, 0.f));
    }
  }
}

// ---------- merged mixing: grid 3200 ([0,1600) spatial, [1600,3200) temporal) ----------
__global__ __launch_bounds__(256) void k_mix_all(
    const float* __restrict__ sfeat, const unsigned short* __restrict__ params_s,
    unsigned short* __restrict__ hid_s,
    const float* __restrict__ tfeat, const unsigned short* __restrict__ params_t,
    unsigned short* __restrict__ hid_t){
  __shared__ float shbuf[2*32*64 + 128*32 + 8];    // 32.8 KB (spatial worst case)
  if(blockIdx.x < 1600)
    mix_body<32,128>(shbuf, sfeat, params_s, hid_s, 1024, blockIdx.x);
  else
    mix_body<8,32>(shbuf, tfeat, params_t, hid_t, 256, blockIdx.x - 1600);
}

// ---------- merged final GEMMs (frag-packed): partial[32][400][256] each ----------
// grid (64, 25): bx<32 -> spatial slab, else temporal slab.
__global__ __launch_bounds__(256, 4) void k_gemm_final(
    const unsigned short* __restrict__ Hs, const unsigned short* __restrict__ WTs,
    float* __restrict__ parts, const unsigned short* __restrict__ Ht,
    const unsigned short* __restrict__ WTt, float* __restrict__ partt){
  const unsigned short *H, *W; float* partial; int KK, ks, ksteps;
  if(blockIdx.x < 32){ H=Hs; W=WTs; partial=parts; KK=1024; ks=blockIdx.x;    ksteps=32; }
  else               { H=Ht; W=WTt; partial=partt; KK=256;  ks=blockIdx.x-32; ksteps=8;  }
  int wave = threadIdx.x >> 6, lane = threadIdx.x & 63;
  int col = lane & 15, kg = lane >> 4;
  int mt = blockIdx.y;
  int kk0 = ks * ksteps;
  int n0 = wave * 64;
  f32x4 acc[4] = {};
  const bf16x8* ap  = (const bf16x8*)H + ((size_t)mt*KK + kk0)*64 + lane;
  const bf16x8* bp0 = (const bf16x8*)W + ((size_t)(4*wave+0)*KK + kk0)*64 + lane;
  const bf16x8* bp1 = (const bf16x8*)W + ((size_t)(4*wave+1)*KK + kk0)*64 + lane;
  const bf16x8* bp2 = (const bf16x8*)W + ((size_t)(4*wave+2)*KK + kk0)*64 + lane;
  const bf16x8* bp3 = (const bf16x8*)W + ((size_t)(4*wave+3)*KK + kk0)*64 + lane;
  #pragma unroll 4
  for(int kk=0; kk<ksteps; kk++){
    bf16x8 af = ap[kk*64];
    bf16x8 b0 = bp0[kk*64], b1 = bp1[kk*64], b2 = bp2[kk*64], b3 = bp3[kk*64];
    acc[0] = __builtin_amdgcn_mfma_f32_16x16x32_bf16(af, b0, acc[0], 0,0,0);
    acc[1] = __builtin_amdgcn_mfma_f32_16x16x32_bf16(af, b1, acc[1], 0,0,0);
    acc[2] = __builtin_amdgcn_mfma_f32_16x16x32_bf16(af, b2, acc[2], 0,0,0);
    acc[3] = __builtin_amdgcn_mfma_f32_16x16x32_bf16(af, b3, acc[3], 0,0,0);
  }
  int rowb = mt*16 + kg*4;
  #pragma unroll
  for(int nt=0; nt<4; nt++)
    #pragma unroll
    for(int r=0; r<4; r++)
      partial[((size_t)ks*400 + rowb + r)*256 + n0 + nt*16 + col] = acc[nt][r];
}

// ---------- finalize both outputs: residual + bias + LN -> out ----------
// grid (400, 2), block 256
template<int NS>
__global__ __launch_bounds__(256) void k_finalize(
    const float* __restrict__ part_s, const float* __restrict__ part_t,
    const float* __restrict__ qs, const float* __restrict__ qt,
    const float* __restrict__ bos, const float* __restrict__ bot,
    const float* __restrict__ gs, const float* __restrict__ gt,
    const float* __restrict__ bes, const float* __restrict__ bet,
    float* __restrict__ out_s, float* __restrict__ out_t){
  __shared__ float rA[4], rB[4];
  int bq = blockIdx.x, j = threadIdx.x;
  const float *partial, *q, *bo, *gam, *bet_;
  float* out;
  if(blockIdx.y == 0){ partial=part_s; q=qs; bo=bos; gam=gs; bet_=bes; out=out_s; }
  else               { partial=part_t; q=qt; bo=bot; gam=gt; bet_=bet; out=out_t; }
  float v = q[bq*256 + j] + bo[j];
  #pragma unroll 8
  for(int s=0;s<NS;s++) v += partial[((size_t)s*400 + bq)*256 + j];
  float s1 = v, s2 = v*v;
  block_reduce2(s1, s2, rA, rB, j);
  float mu = s1 * (1.f/256.f);
  float var = s2 * (1.f/256.f) - mu*mu;
  float rstd = rsqrtf(var + 1e-5f);
  out[bq*256 + j] = (v - mu) * rstd * gam[j] + bet_[j];
}

// ---------------------------------------------------------------------------
extern "C" void kernel_launch(void* const* d_in, const int* in_sizes, int n_in,
                              void* d_out, int out_size, void* d_ws, size_t ws_size,
                              hipStream_t stream){
  const float* feat0 = (const float*)d_in[0];
  const float* feat1 = (const float*)d_in[1];
  const float* feat2 = (const float*)d_in[2];
  const float* feat3 = (const float*)d_in[3];
  const float* boxes = (const float*)d_in[4];
  const float* qs    = (const float*)d_in[5];
  const float* qt    = (const float*)d_in[6];
  const float* Woff  = (const float*)d_in[7];
  const float* boff  = (const float*)d_in[8];
  const float* Wps   = (const float*)d_in[9];
  const float* bps   = (const float*)d_in[10];
  const float* Wos   = (const float*)d_in[11];
  const float* bos   = (const float*)d_in[12];
  const float* gs    = (const float*)d_in[13];
  const float* bes   = (const float*)d_in[14];
  const float* Wpt   = (const float*)d_in[15];
  const float* bpt   = (const float*)d_in[16];
  const float* Wot   = (const float*)d_in[17];
  const float* bot   = (const float*)d_in[18];
  const float* gt    = (const float*)d_in[19];
  const float* bet   = (const float*)d_in[20];

  char* ws = (char*)d_ws;
  // arena: [l][g][b][p][t][c64] bf16, 89,128,960 B at ws+0 (dead after sample)
  unsigned short* arena  = (unsigned short*)(ws + 0);
  float* part_s          = (float*)(ws + 0);            // 13,107,200 B (NS=32)
  float* part_t          = (float*)(ws + 52428800);     // 13,107,200 B
  unsigned short* qsP    = (unsigned short*)(ws + 89128960);    //   204,800
  unsigned short* qtP    = (unsigned short*)(ws + 89333760);    //   204,800
  unsigned short* WpsP   = (unsigned short*)(ws + 89538560);    // 16,777,216
  unsigned short* WptP   = (unsigned short*)(ws + 106315776);   //  8,912,896
  unsigned short* WosP   = (unsigned short*)(ws + 115228672);   // 16,777,216
  unsigned short* WotP   = (unsigned short*)(ws + 132005888);   //  4,194,304
  float* sfeat           = (float*)(ws + 137461760);
  float* tfeat           = (float*)(ws + 150568960);
  unsigned short* hid_s  = (unsigned short*)(ws + 153845760);   // 26,214,400 (packed)
  unsigned short* hid_t  = (unsigned short*)(ws + 180060160);   //  6,553,600 (packed)
  unsigned short* params_s = (unsigned short*)(ws + 186613760); // 26,214,400 (bf16)
  unsigned short* params_t = (unsigned short*)(ws + 212828160); // 13,926,400 (bf16)
  int2* tapbuf           = (int2*)(ws + 226754560);             //  6,553,600
  float* out_s = (float*)d_out;
  float* out_t = out_s + 102400;

  // 1. PREP: feat transposes + weight packs + query packs (one launch)
  k_prep<<<16776, 256, 0, stream>>>(feat0, feat1, feat2, feat3, arena,
                                    Wps, Wpt, Wos, Wot, WpsP, WptP, WosP, WotP,
                                    (const float4*)qs, (const float4*)qt, qsP, qtP);
  // 2. offsets -> tap table
  k_offsets<<<400, 384, 0, stream>>>(qs, Woff, boff, boxes, tapbuf);
  // 3. sampling + params GEMMs in ONE launch (independent; overlap)
  k_sample_params<<<5520, 256, 0, stream>>>(arena, tapbuf, sfeat, tfeat,
                                            qsP, WpsP, bps, params_s,
                                            qtP, WptP, bpt, params_t);
  // 4. adaptive mixing (merged s+t; hid written frag-packed)
  k_mix_all<<<3200, 256, 0, stream>>>(sfeat, params_s, hid_s,
                                      tfeat, params_t, hid_t);
  // 5. final GEMMs (NS=32; partials alias dead arena region)
  k_gemm_final<<<dim3(64, 25), 256, 0, stream>>>(hid_s, WosP, part_s,
                                                 hid_t, WotP, part_t);
  // 6. finalize (merged)
  k_finalize<32><<<dim3(400, 2), 256, 0, stream>>>(
      part_s, part_t, qs, qt, bos, bot, gs, gt, bes, bet, out_s, out_t);
}